// Round 7
// baseline (348.868 us; speedup 1.0000x reference)
//
#include <hip/hip_runtime.h>

#define B_ 8
#define K_ 4096
#define IN_ 512
#define H_ 8
#define D_ 64
#define HD_ 512  // H_*D_

typedef short bf16x8 __attribute__((ext_vector_type(8)));
typedef float f32x4 __attribute__((ext_vector_type(4)));
typedef unsigned short u16;
typedef unsigned short us8v __attribute__((ext_vector_type(8)));
typedef unsigned short us4v __attribute__((ext_vector_type(4)));

__device__ inline u16 f2bf_rn(float f) {
  unsigned u = __float_as_uint(f);
  u += 0x7fffu + ((u >> 16) & 1u);
  return (u16)(u >> 16);
}
__device__ inline float bf2f(u16 h) {
  return __uint_as_float(((unsigned)h) << 16);
}

// async global->LDS, 16B per lane. LDS dest is wave-uniform base + lane*16.
__device__ inline void gl_lds16(const u16* g, u16* l) {
  __builtin_amdgcn_global_load_lds(
      (const __attribute__((address_space(1))) unsigned int*)g,
      (__attribute__((address_space(3))) unsigned int*)l, 16, 0, 0);
}

// =========================================================================
// ws layout (bytes), fast path:
//   region0 [0, 33554432):
//     phase1: xt_hi [B][IN][K] bf16 (32MB)
//     phase2 (after k_gram): Ahi @0 (4MB), Alo @4MB, Wft @8MB (4MB)
//   xt_lo  @33554432  (32MB)   -- phase2: yb (y as bf16, 32MB)
//   G      @67108864  [B][IN][IN] f32 (8MB)
//   Ghi    @75497472 (4MB)   Glo @79691776 (4MB)
//   Wqt_hi @83886080 (512KB) Wqt_lo @84410368
//   Wkt_hi @84934656         Wkt_lo @85458944
//   bfin   @85983232 (16KB)  svec @85999616 (16KB)
//   NEED = 86016000
// =========================================================================

// x (B,K,IN) f32 -> xt_hi/xt_lo (B,IN,K) bf16 split, + column sums (atomic)
__global__ __launch_bounds__(256) void k_cvt_x(const float* __restrict__ x,
                                               u16* __restrict__ xt_hi,
                                               u16* __restrict__ xt_lo,
                                               float* __restrict__ svec) {
  const int kt = blockIdx.x, ct = blockIdx.y, b = blockIdx.z;
  __shared__ float Xs[64][65];
  const int tid = threadIdx.x;
  const float* src = x + ((size_t)b * K_ + kt * 64) * IN_ + ct * 64;
#pragma unroll
  for (int r = 0; r < 4; ++r) {
    int idx = tid + 256 * r;  // 0..1023
    int k = idx >> 4, c4 = (idx & 15) * 4;
    f32x4 v = *(const f32x4*)(src + (size_t)k * IN_ + c4);
    Xs[k][c4 + 0] = v[0];
    Xs[k][c4 + 1] = v[1];
    Xs[k][c4 + 2] = v[2];
    Xs[k][c4 + 3] = v[3];
  }
  __syncthreads();
  if (tid < 64) {
    float s = 0.f;
#pragma unroll
    for (int k = 0; k < 64; ++k) s += Xs[k][tid];
    atomicAdd(&svec[b * IN_ + ct * 64 + tid], s);
  }
#pragma unroll
  for (int r = 0; r < 2; ++r) {
    int idx = tid + 256 * r;  // 0..511
    int c = idx >> 3, ck = (idx & 7) * 8;
    us8v hv, lv;
#pragma unroll
    for (int j = 0; j < 8; ++j) {
      float f = Xs[ck + j][c];
      u16 h = f2bf_rn(f);
      float lo = f - bf2f(h);
      hv[j] = h;
      lv[j] = f2bf_rn(lo);
    }
    size_t off = ((size_t)(b * IN_ + ct * 64 + c)) * K_ + kt * 64 + ck;
    *(us8v*)(xt_hi + off) = hv;
    *(us8v*)(xt_lo + off) = lv;
  }
}

// y (B,K,IN) f32 -> yb bf16 (same layout). Runs after k_gram frees xt_lo.
__global__ __launch_bounds__(256) void k_cvt_y(const float* __restrict__ y,
                                               u16* __restrict__ yb) {
  size_t i = ((size_t)blockIdx.x * 256 + threadIdx.x) * 8;
  f32x4 v0 = *(const f32x4*)(y + i);
  f32x4 v1 = *(const f32x4*)(y + i + 4);
  us8v o;
  o[0] = f2bf_rn(v0[0]); o[1] = f2bf_rn(v0[1]);
  o[2] = f2bf_rn(v0[2]); o[3] = f2bf_rn(v0[3]);
  o[4] = f2bf_rn(v1[0]); o[5] = f2bf_rn(v1[1]);
  o[6] = f2bf_rn(v1[2]); o[7] = f2bf_rn(v1[3]);
  *(us8v*)(yb + i) = o;
}

// Wq/Wk (512x512) -> transposed bf16 hi/lo: Wt[dcol][c] = W[c][dcol]
__global__ __launch_bounds__(256) void k_cvt_w(
    const float* __restrict__ Wq, const float* __restrict__ Wk,
    u16* __restrict__ Wqt_hi, u16* __restrict__ Wqt_lo,
    u16* __restrict__ Wkt_hi, u16* __restrict__ Wkt_lo) {
  const int ti = blockIdx.x, tj = blockIdx.y;
  const float* src = blockIdx.z ? Wk : Wq;
  u16* dhi = blockIdx.z ? Wkt_hi : Wqt_hi;
  u16* dlo = blockIdx.z ? Wkt_lo : Wqt_lo;
  __shared__ float T[64][65];
  const int tid = threadIdx.x;
#pragma unroll
  for (int r = 0; r < 4; ++r) {
    int idx = tid + 256 * r;
    int rr = idx >> 4, c4 = (idx & 15) * 4;
    f32x4 v = *(const f32x4*)(src + (size_t)(tj * 64 + rr) * 512 + ti * 64 + c4);
    T[rr][c4 + 0] = v[0]; T[rr][c4 + 1] = v[1];
    T[rr][c4 + 2] = v[2]; T[rr][c4 + 3] = v[3];
  }
  __syncthreads();
#pragma unroll
  for (int r = 0; r < 2; ++r) {
    int idx = tid + 256 * r;
    int d = idx >> 3, ck = (idx & 7) * 8;
    us8v hv, lv;
#pragma unroll
    for (int j = 0; j < 8; ++j) {
      float f = T[ck + j][d];
      u16 h = f2bf_rn(f);
      hv[j] = h;
      lv[j] = f2bf_rn(f - bf2f(h));
    }
    size_t off = (size_t)(ti * 64 + d) * 512 + tj * 64 + ck;
    *(us8v*)(dhi + off) = hv;
    *(us8v*)(dlo + off) = lv;
  }
}

#define GP 72  // padded LDS row (64 bf16 + 8) = 144 B (used by k_attn3)

// G_b += X^T X: 256x256 block tile, 8 waves (2x4), wave tile 128x64.
// Halves LDS bytes/FLOP vs the old 64x64 wave tile ((M+N)/MN: 128/4096 ->
// 192/8192), so per CU-iter MFMA (~3725 cyc) > LDS (~3000 cyc): MFMA-bound.
// grid: 3 upper 256-pairs x 8 b x 8 kc = 192 blocks, 1 block/CU (128KB LDS).
// Counted-vmcnt pipeline (R6): STAGE(t+1) -> vmcnt(L) (own tile-t DMA only)
// -> raw s_barrier -> ds_read+MFMA -> raw s_barrier. Swizzle (R5,
// conflict-free, both sides): 16B slot ^ ((row>>1)&3).
// Diag-256 blocks compute the full square: below-diagonal values are
// correct (sum x_i x_j), harmless extra atomics; cvt_g only reads upper.
// Per-element MFMA product/K order unchanged; G atomic order was already
// nondeterministic, so kc-chain regrouping is numerics-equivalent class.
__global__ __launch_bounds__(512, 2) void k_gram_mfma(
    const u16* __restrict__ xt_hi, const u16* __restrict__ xt_lo,
    float* __restrict__ G) {
  const int fid = blockIdx.x;     // 0..191
  const int kc = fid & 7;         // XCD-affine: same (b,kc) over pp -> same XCD
  const int sl = fid >> 3;        // 0..23
  const int b = sl & 7;
  const int pp = sl >> 3;         // 0..2 -> (0,0),(0,1),(1,1)
  const int ti = pp >> 1, tj = (pp + 1) >> 1;
  const bool diag = (ti == tj);
  __shared__ u16 P[2][4 * 256 * 32];  // 128 KB: [buf][ih|il|jh|jl][256][32]
  const int AOFF = 256 * 32;
  const int tid = threadIdx.x;
  const int wave = tid >> 6, lane = tid & 63;
  const int wm = wave & 1, wn = wave >> 1;  // wm 0..1 (128-row half), wn 0..3
  const int m16 = lane & 15, quad = lane >> 4;
  const size_t base_i = ((size_t)(b * IN_ + ti * 256)) * K_;
  const size_t base_j = ((size_t)(b * IN_ + tj * 256)) * K_;
  const int sr = lane >> 2, sslot = lane & 3;  // staging: 16 rows x 4 slots
  const int boff_h = diag ? 0 : 2 * AOFF;
  const int boff_l = diag ? AOFF : 3 * AOFF;

  f32x4 zf = {0.f, 0.f, 0.f, 0.f};
  f32x4 acc[8][4];
#pragma unroll
  for (int mt = 0; mt < 8; ++mt)
#pragma unroll
    for (int nt = 0; nt < 4; ++nt) acc[mt][nt] = zf;
  const int kbeg = kc * 512;

  auto STAGE = [&](int t, int buf) {
    const int k0 = kbeg + t * 32;
    u16* Pb = &P[buf][0];
#pragma unroll
    for (int g = 0; g < 2; ++g) {
      int rbase = wave * 32 + g * 16;  // wave-uniform, mult of 16, 0..240
      int r = rbase + sr;              // per-lane row 0..255
      size_t go = (size_t)r * K_ + k0 + ((sslot ^ ((sr >> 1) & 3)) << 3);
      int lo = rbase * 32;             // wave-uniform LDS base
      gl_lds16(xt_hi + base_i + go, Pb + lo);
      gl_lds16(xt_lo + base_i + go, Pb + AOFF + lo);
      if (!diag) {
        gl_lds16(xt_hi + base_j + go, Pb + 2 * AOFF + lo);
        gl_lds16(xt_lo + base_j + go, Pb + 3 * AOFF + lo);
      }
    }
  };

  STAGE(0, 0);
  int cur = 0;
  const int ac = ((quad ^ ((m16 >> 1) & 3)) << 3);  // conflict-free swizzle
  for (int t = 0; t < 16; ++t) {
    if (t < 15) {
      STAGE(t + 1, cur ^ 1);
      // drain own tile-t DMA only; tile t+1's loads stay in flight
      if (diag) asm volatile("s_waitcnt vmcnt(4)" ::: "memory");
      else      asm volatile("s_waitcnt vmcnt(8)" ::: "memory");
    } else {
      asm volatile("s_waitcnt vmcnt(0)" ::: "memory");
    }
    __builtin_amdgcn_s_barrier();  // all waves' tile-t DMA visible
    __builtin_amdgcn_sched_barrier(0);
    const u16* Pb = &P[cur][0];
    bf16x8 bh[4], bl[4];
#pragma unroll
    for (int nt = 0; nt < 4; ++nt) {
      int br = (wn * 64 + nt * 16 + m16) * 32 + ac;
      bh[nt] = *(const bf16x8*)(Pb + boff_h + br);
      bl[nt] = *(const bf16x8*)(Pb + boff_l + br);
    }
#pragma unroll
    for (int mt = 0; mt < 8; ++mt) {
      int ar = (wm * 128 + mt * 16 + m16) * 32 + ac;
      bf16x8 ah = *(const bf16x8*)(Pb + ar);
      bf16x8 al = *(const bf16x8*)(Pb + AOFF + ar);
#pragma unroll
      for (int nt = 0; nt < 4; ++nt) {
        acc[mt][nt] = __builtin_amdgcn_mfma_f32_16x16x32_bf16(
            ah, bh[nt], acc[mt][nt], 0, 0, 0);
        acc[mt][nt] = __builtin_amdgcn_mfma_f32_16x16x32_bf16(
            ah, bl[nt], acc[mt][nt], 0, 0, 0);
        acc[mt][nt] = __builtin_amdgcn_mfma_f32_16x16x32_bf16(
            al, bh[nt], acc[mt][nt], 0, 0, 0);
      }
    }
    __builtin_amdgcn_s_barrier();  // readers done before buf re-staged
    cur ^= 1;
  }
  float* Gb = G + (size_t)b * IN_ * IN_;
#pragma unroll
  for (int mt = 0; mt < 8; ++mt)
#pragma unroll
    for (int nt = 0; nt < 4; ++nt)
#pragma unroll
      for (int r = 0; r < 4; ++r) {
        int gi = ti * 256 + wm * 128 + mt * 16 + quad * 4 + r;
        int gj = tj * 256 + wn * 64 + nt * 16 + m16;
        atomicAdd(&Gb[(size_t)gi * IN_ + gj], acc[mt][nt][r]);
      }
}

// G f32 (upper 64-tiles) -> Ghi/Glo bf16, mirroring lower tiles
__global__ __launch_bounds__(256) void k_cvt_g(const float* __restrict__ G,
                                               u16* __restrict__ Ghi,
                                               u16* __restrict__ Glo) {
  const int ti = blockIdx.x, tj = blockIdx.y, b = blockIdx.z;
  if (tj < ti) return;
  const float* Gb = G + (size_t)b * IN_ * IN_;
  u16* ghb = Ghi + (size_t)b * IN_ * IN_;
  u16* glb = Glo + (size_t)b * IN_ * IN_;
  __shared__ float T[64][65];
  const int tid = threadIdx.x;
#pragma unroll
  for (int r = 0; r < 4; ++r) {
    int idx = tid + 256 * r;
    int rr = idx >> 4, c4 = (idx & 15) * 4;
    f32x4 v = *(const f32x4*)(Gb + (size_t)(ti * 64 + rr) * IN_ + tj * 64 + c4);
    T[rr][c4 + 0] = v[0]; T[rr][c4 + 1] = v[1];
    T[rr][c4 + 2] = v[2]; T[rr][c4 + 3] = v[3];
  }
  __syncthreads();
#pragma unroll
  for (int r = 0; r < 2; ++r) {
    int idx = tid + 256 * r;
    int rr = idx >> 3, ck = (idx & 7) * 8;
    us8v hv, lv;
#pragma unroll
    for (int j = 0; j < 8; ++j) {
      float f = T[rr][ck + j];
      u16 h = f2bf_rn(f);
      hv[j] = h;
      lv[j] = f2bf_rn(f - bf2f(h));
    }
    size_t off = (size_t)(ti * 64 + rr) * IN_ + tj * 64 + ck;
    *(us8v*)(ghb + off) = hv;
    *(us8v*)(glb + off) = lv;
  }
  if (ti != tj) {
#pragma unroll
    for (int r = 0; r < 2; ++r) {
      int idx = tid + 256 * r;
      int rr = idx >> 3, ck = (idx & 7) * 8;
      us8v hv, lv;
#pragma unroll
      for (int j = 0; j < 8; ++j) {
        float f = T[ck + j][rr];  // mirrored element
        u16 h = f2bf_rn(f);
        hv[j] = h;
        lv[j] = f2bf_rn(f - bf2f(h));
      }
      size_t off = (size_t)(tj * 64 + rr) * IN_ + ti * 64 + ck;
      *(us8v*)(ghb + off) = hv;
      *(us8v*)(glb + off) = lv;
    }
  }
}

// A[hb] = Wqt_h (64x512) @ G_b (512x512), 3-product MFMA. bf16 hi/lo out.
// m97-style gload_lds staging + both-sides XOR swizzle.
__global__ __launch_bounds__(256) void k_aall_mfma(
    const u16* __restrict__ Wqt_hi, const u16* __restrict__ Wqt_lo,
    const u16* __restrict__ Ghi, const u16* __restrict__ Glo,
    u16* __restrict__ Ahi, u16* __restrict__ Alo) {
  const int ct = blockIdx.x;  // c' tile 0..7
  const int hb = blockIdx.y;  // h*8+b
  const int h = hb >> 3, b = hb & 7;
  __shared__ u16 S[4 * 64 * 64];  // Ah | Al | Bh | Bl, 32KB (epilogue reuses)
  u16* Ah = S;
  u16* Al = S + 64 * 64;
  u16* Bh = S + 2 * 64 * 64;
  u16* Bl = S + 3 * 64 * 64;
  const int tid = threadIdx.x;
  const int wave = tid >> 6, lane = tid & 63;
  const int m16 = lane & 15, quad = lane >> 4;
  const u16* Abase_h = Wqt_hi + (size_t)(h * 64) * IN_;
  const u16* Abase_l = Wqt_lo + (size_t)(h * 64) * IN_;
  const u16* Bbase_h = Ghi + (size_t)b * IN_ * IN_ + (size_t)(ct * 64) * IN_;
  const u16* Bbase_l = Glo + (size_t)b * IN_ * IN_ + (size_t)(ct * 64) * IN_;
  const int lrow = lane >> 3;
  const int lcol = ((lane & 7) * 8) ^ (lrow << 3);
  const size_t loff = (size_t)lrow * IN_ + lcol;
  f32x4 zf = {0.f, 0.f, 0.f, 0.f};
  f32x4 acc[4] = {zf, zf, zf, zf};
  for (int k0 = 0; k0 < IN_; k0 += 64) {
    __syncthreads();
#pragma unroll
    for (int r = 0; r < 2; ++r) {
      int rg = wave * 2 + r;  // 0..7
      size_t go = (size_t)(rg * 8) * IN_ + k0 + loff;
      int lo = rg * 8 * 64;
      gl_lds16(Abase_h + go, &Ah[lo]);
      gl_lds16(Abase_l + go, &Al[lo]);
      gl_lds16(Bbase_h + go, &Bh[lo]);
      gl_lds16(Bbase_l + go, &Bl[lo]);
    }
    __syncthreads();
#pragma unroll
    for (int kk = 0; kk < 64; kk += 32) {
      const int ac = (kk + quad * 8) ^ ((m16 & 7) << 3);
      int arow = (wave * 16 + m16) * 64 + ac;
      bf16x8 ah = *(const bf16x8*)&Ah[arow];
      bf16x8 al = *(const bf16x8*)&Al[arow];
#pragma unroll
      for (int n = 0; n < 4; ++n) {
        int brow = (n * 16 + m16) * 64 + ac;
        bf16x8 bh = *(const bf16x8*)&Bh[brow];
        bf16x8 bl = *(const bf16x8*)&Bl[brow];
        acc[n] = __builtin_amdgcn_mfma_f32_16x16x32_bf16(ah, bh, acc[n], 0, 0, 0);
        acc[n] = __builtin_amdgcn_mfma_f32_16x16x32_bf16(ah, bl, acc[n], 0, 0, 0);
        acc[n] = __builtin_amdgcn_mfma_f32_16x16x32_bf16(al, bh, acc[n], 0, 0, 0);
      }
    }
  }
  __syncthreads();
  float* Sf = (float*)S;  // 64*68*4 = 17408 B <= 32KB
#pragma unroll
  for (int n = 0; n < 4; ++n)
#pragma unroll
    for (int r = 0; r < 4; ++r) {
      int d = wave * 16 + quad * 4 + r;
      int cc = n * 16 + m16;
      Sf[d * 68 + cc] = acc[n][r];
    }
  __syncthreads();
#pragma unroll
  for (int r = 0; r < 2; ++r) {
    int idx = tid + 256 * r;
    int d = idx >> 3, ck = (idx & 7) * 8;
    us8v hv, lv;
#pragma unroll
    for (int j = 0; j < 8; ++j) {
      float f = Sf[d * 68 + ck + j];
      u16 h2 = f2bf_rn(f);
      hv[j] = h2;
      lv[j] = f2bf_rn(f - bf2f(h2));
    }
    size_t off = ((size_t)hb * 64 + d) * IN_ + ct * 64 + ck;
    *(us8v*)(Ahi + off) = hv;
    *(us8v*)(Alo + off) = lv;
  }
}

// per (h,b): E = A @ Wk (MFMA 3-product) + bias, softmax, bfin,
// then Wft[q][c] = bf16((g * sum_e Wv[c,e]*attn[q,e] + Wp[c,q])/(1+g)) via MFMA
__global__ __launch_bounds__(256) void k_attn3(
    const u16* __restrict__ Ahi, const u16* __restrict__ Alo,
    const u16* __restrict__ Wqt_hi, const u16* __restrict__ Wqt_lo,
    const u16* __restrict__ Wkt_hi, const u16* __restrict__ Wkt_lo,
    const float* __restrict__ Wv, const float* __restrict__ Wp,
    const float* __restrict__ bq, const float* __restrict__ bk,
    const float* __restrict__ bv, const float* __restrict__ gamma,
    const float* __restrict__ svec, u16* __restrict__ Wft,
    float* __restrict__ bfin) {
  const int h = blockIdx.x, b = blockIdx.y;
  const int hb = h * B_ + b;
  const int tid = threadIdx.x;
  const int wave = tid >> 6, lane = tid & 63;
  const int m16 = lane & 15, quad = lane >> 4;
  __shared__ u16 S[4 * 64 * GP];
  __shared__ float Esh[64][65];
  __shared__ float t1[64], t2[64];
  u16* Ah = S;
  u16* Al = S + 64 * GP;
  u16* Bh = S + 2 * 64 * GP;
  u16* Bl = S + 3 * 64 * GP;

  if (tid < 64) {
    float s = 0.f;
    const u16* wh = Wkt_hi + (size_t)(h * 64 + tid) * IN_;
    const u16* wl = Wkt_lo + (size_t)(h * 64 + tid) * IN_;
    const float* sv = svec + b * IN_;
    for (int c = 0; c < IN_; c += 8) {
      us8v hv = *(const us8v*)(wh + c);
      us8v lv = *(const us8v*)(wl + c);
#pragma unroll
      for (int j = 0; j < 8; ++j)
        s += sv[c + j] * (bf2f(hv[j]) + bf2f(lv[j]));
    }
    t1[tid] = s;
  } else if (tid < 128) {
    int d = tid - 64;
    float s = 0.f;
    const u16* wh = Wqt_hi + (size_t)(h * 64 + d) * IN_;
    const u16* wl = Wqt_lo + (size_t)(h * 64 + d) * IN_;
    const float* sv = svec + b * IN_;
    for (int c = 0; c < IN_; c += 8) {
      us8v hv = *(const us8v*)(wh + c);
      us8v lv = *(const us8v*)(wl + c);
#pragma unroll
      for (int j = 0; j < 8; ++j)
        s += sv[c + j] * (bf2f(hv[j]) + bf2f(lv[j]));
    }
    t2[d] = s;
  }

  const u16* Abase_h = Ahi + (size_t)hb * 64 * IN_;
  const u16* Abase_l = Alo + (size_t)hb * 64 * IN_;
  const u16* Bbase_h = Wkt_hi + (size_t)(h * 64) * IN_;
  const u16* Bbase_l = Wkt_lo + (size_t)(h * 64) * IN_;
  f32x4 zf = {0.f, 0.f, 0.f, 0.f};
  f32x4 acc[4] = {zf, zf, zf, zf};
  for (int k0 = 0; k0 < IN_; k0 += 64) {
    __syncthreads();
#pragma unroll
    for (int r = 0; r < 2; ++r) {
      int idx = tid + 256 * r;
      int row = idx >> 3, ck = (idx & 7) * 8;
      int lo = row * GP + ck;
      *(us8v*)&Ah[lo] = *(const us8v*)(Abase_h + (size_t)row * IN_ + k0 + ck);
      *(us8v*)&Al[lo] = *(const us8v*)(Abase_l + (size_t)row * IN_ + k0 + ck);
      *(us8v*)&Bh[lo] = *(const us8v*)(Bbase_h + (size_t)row * IN_ + k0 + ck);
      *(us8v*)&Bl[lo] = *(const us8v*)(Bbase_l + (size_t)row * IN_ + k0 + ck);
    }
    __syncthreads();
#pragma unroll
    for (int kk = 0; kk < 64; kk += 32) {
      int arow = (wave * 16 + m16) * GP + kk + quad * 8;
      bf16x8 ah = *(const bf16x8*)&Ah[arow];
      bf16x8 al = *(const bf16x8*)&Al[arow];
#pragma unroll
      for (int n = 0; n < 4; ++n) {
        int brow = (n * 16 + m16) * GP + kk + quad * 8;
        bf16x8 bh = *(const bf16x8*)&Bh[brow];
        bf16x8 bl = *(const bf16x8*)&Bl[brow];
        acc[n] = __builtin_amdgcn_mfma_f32_16x16x32_bf16(ah, bh, acc[n], 0, 0, 0);
        acc[n] = __builtin_amdgcn_mfma_f32_16x16x32_bf16(ah, bl, acc[n], 0, 0, 0);
        acc[n] = __builtin_amdgcn_mfma_f32_16x16x32_bf16(al, bh, acc[n], 0, 0, 0);
      }
    }
  }
  __syncthreads();
#pragma unroll
  for (int n = 0; n < 4; ++n)
#pragma unroll
    for (int r = 0; r < 4; ++r) {
      int d = wave * 16 + quad * 4 + r;
      int e = n * 16 + m16;
      float bqd = bq[h * D_ + d], bke = bk[h * D_ + e];
      Esh[d][e] = acc[n][r] + bqd * t1[e] + t2[d] * bke + (float)K_ * bqd * bke;
    }
  __syncthreads();
  const float g = gamma[h];
  const float inv1g = 1.f / (1.f + g);
  if (tid < 64) {
    float m = -1e30f;
    for (int e = 0; e < 64; ++e) m = fmaxf(m, Esh[tid][e]);
    float ssum = 0.f;
    for (int e = 0; e < 64; ++e) {
      float p = __expf(Esh[tid][e] - m);
      Esh[tid][e] = p;
      ssum += p;
    }
    float inv = 1.f / ssum;
    float bsum = 0.f;
    for (int e = 0; e < 64; ++e) {
      Esh[tid][e] *= inv;
      bsum += bv[h * D_ + e] * Esh[tid][e];
    }
    bfin[hb * D_ + tid] = g * bsum * inv1g;
  }
  __syncthreads();

  bf16x8 bfr[4][2];
#pragma unroll
  for (int n = 0; n < 4; ++n)
#pragma unroll
    for (int kk = 0; kk < 2; ++kk)
#pragma unroll
      for (int j = 0; j < 8; ++j)
        bfr[n][kk][j] = f2bf_rn(Esh[n * 16 + m16][kk * 32 + quad * 8 + j]);

  u16* Wf = Wft + (size_t)hb * D_ * IN_;
#pragma unroll
  for (int mt = 0; mt < 8; ++mt) {
    f32x4 a4[4] = {zf, zf, zf, zf};
#pragma unroll
    for (int kk = 0; kk < 2; ++kk) {
      int c = wave * 128 + mt * 16 + m16;
      const float* wv = Wv + (size_t)c * HD_ + h * D_ + kk * 32 + quad * 8;
      f32x4 v0 = *(const f32x4*)wv;
      f32x4 v1 = *(const f32x4*)(wv + 4);
      bf16x8 af;
      af[0] = f2bf_rn(v0[0]); af[1] = f2bf_rn(v0[1]);
      af[2] = f2bf_rn(v0[2]); af[3] = f2bf_rn(v0[3]);
      af[4] = f2bf_rn(v1[0]); af[5] = f2bf_rn(v1[1]);
      af[6] = f2bf_rn(v1[2]); af[7] = f2bf_rn(v1[3]);
#pragma unroll
      for (int n = 0; n < 4; ++n)
        a4[n] = __builtin_amdgcn_mfma_f32_16x16x32_bf16(af, bfr[n][kk], a4[n], 0, 0, 0);
    }
    int cb = wave * 128 + mt * 16 + quad * 4;
#pragma unroll
    for (int n = 0; n < 4; ++n) {
      int q = n * 16 + m16;
      us4v st;
#pragma unroll
      for (int r = 0; r < 4; ++r) {
        float val = (g * a4[n][r] + Wp[(size_t)(cb + r) * D_ + q]) * inv1g;
        st[r] = f2bf_rn(val);
      }
      *(us4v*)(Wf + (size_t)q * IN_ + cb) = st;
    }
  }
}

// out = y @ Wft^T (+bfin), 2 heads/block, 256 rows/block, grid (16 kt, 32).
// 2-phase pipeline: reg-stage next Wft tile + next y frags during MFMA of
// current tile; double-buffered 16KB LDS, XOR-swizzled (col ^ ((row&7)<<3))
// so ds_read_b128 is conflict-optimal on 128B rows. y pre-converted to bf16
// (k_cvt_y) -> no in-loop cvt VALU, half the y bytes.
__global__ __launch_bounds__(256, 2) void k_out_mfma(
    const u16* __restrict__ yb, const u16* __restrict__ Wft,
    const float* __restrict__ bfin, float* __restrict__ out) {
  const int kt = blockIdx.x;
  const int b = blockIdx.y & 7, hq = blockIdx.y >> 3;  // hq 0..3
  const int h0 = hq * 2;
  __shared__ u16 Wsh[2][2 * 64 * 64];  // [buf][row*64+col], row=i*64+q, 16KB each
  const int tid = threadIdx.x, wave = tid >> 6, lane = tid & 63;
  const int m16 = lane & 15, quad = lane >> 4;
  const int swz = (m16 & 7) << 3;

  us8v stg[4];
  auto LOAD = [&](int c0) {
#pragma unroll
    for (int r = 0; r < 4; ++r) {
      int idx = tid + 256 * r;  // 0..1023
      int row = idx >> 3, ck = (idx & 7) * 8;
      int i = row >> 6, q = row & 63;
      const u16* src =
          Wft + ((size_t)((h0 + i) * 8 + b) * 64 + q) * IN_ + c0 + ck;
      stg[r] = *(const us8v*)src;
    }
  };
  auto WRITE = [&](int buf) {
#pragma unroll
    for (int r = 0; r < 4; ++r) {
      int idx = tid + 256 * r;
      int row = idx >> 3, ck = (idx & 7) * 8;
      *(us8v*)&Wsh[buf][row * 64 + (ck ^ ((row & 7) << 3))] = stg[r];
    }
  };
  bf16x8 yf[2][4];  // [kk][ms]
  auto LOADY = [&](bf16x8 (*yd)[4], int c0) {
#pragma unroll
    for (int kk = 0; kk < 2; ++kk)
#pragma unroll
      for (int ms = 0; ms < 4; ++ms) {
        int row = kt * 256 + wave * 64 + ms * 16 + m16;
        yd[kk][ms] = *(const bf16x8*)(yb + ((size_t)b * K_ + row) * IN_ + c0 +
                                      kk * 32 + quad * 8);
      }
  };

  f32x4 zf = {0.f, 0.f, 0.f, 0.f};
  f32x4 acc[4][2][4];  // [ms][i][nt]
#pragma unroll
  for (int ms = 0; ms < 4; ++ms)
#pragma unroll
    for (int i = 0; i < 2; ++i)
#pragma unroll
      for (int nt = 0; nt < 4; ++nt) acc[ms][i][nt] = zf;

  LOAD(0);
  LOADY(yf, 0);
  WRITE(0);
  __syncthreads();
  int cur = 0;
  for (int c0 = 0; c0 < IN_; c0 += 64) {
    const bool more = (c0 + 64 < IN_);
    bf16x8 yn[2][4];
    if (more) {
      LOAD(c0 + 64);
      LOADY(yn, c0 + 64);
    }
#pragma unroll
    for (int kk = 0; kk < 2; ++kk)
#pragma unroll
      for (int i = 0; i < 2; ++i)
#pragma unroll
        for (int nt = 0; nt < 4; ++nt) {
          int brow = i * 64 + nt * 16 + m16;
          bf16x8 bb = *(const bf16x8*)&Wsh[cur][brow * 64 +
                                               ((kk * 32 + quad * 8) ^ swz)];
#pragma unroll
          for (int ms = 0; ms < 4; ++ms)
            acc[ms][i][nt] = __builtin_amdgcn_mfma_f32_16x16x32_bf16(
                yf[kk][ms], bb, acc[ms][i][nt], 0, 0, 0);
        }
    if (more) {
      WRITE(cur ^ 1);
      __syncthreads();
      cur ^= 1;
#pragma unroll
      for (int kk = 0; kk < 2; ++kk)
#pragma unroll
        for (int ms = 0; ms < 4; ++ms) yf[kk][ms] = yn[kk][ms];
    }
  }

#pragma unroll
  for (int i = 0; i < 2; ++i) {
    float* ob = out + (((size_t)b * H_ + h0 + i) * K_) * D_;
    const int hb = (h0 + i) * 8 + b;
#pragma unroll
    for (int ms = 0; ms < 4; ++ms)
#pragma unroll
      for (int nt = 0; nt < 4; ++nt) {
        int col = nt * 16 + m16;
        float bf = bfin[hb * D_ + col];
#pragma unroll
        for (int r = 0; r < 4; ++r) {
          int row = kt * 256 + wave * 64 + ms * 16 + quad * 4 + r;
          ob[(size_t)row * D_ + col] = acc[ms][i][nt][r] + bf;
        }
      }
  }
}

// =========================================================================
// Fallback f32 path (round-1 kernels), used if ws_size is too small
// =========================================================================
__global__ __launch_bounds__(256) void k_gram(const float* __restrict__ x,
                                              float* __restrict__ G,
                                              float* __restrict__ svec) {
  const int it = blockIdx.x, jt = blockIdx.y, b = blockIdx.z;
  if (jt < it) return;
  __shared__ float Xi[16][64];
  __shared__ float Xj[16][64];
  const float* Xb = x + (size_t)b * K_ * IN_;
  const int tx = threadIdx.x, ty = threadIdx.y;
  const int tid = ty * 16 + tx;
  const int i0 = it * 64, j0 = jt * 64;
  const bool diag = (it == jt);
  float acc[4][4] = {};
  float ssum = 0.f;
  for (int k0 = 0; k0 < K_; k0 += 16) {
#pragma unroll
    for (int r = 0; r < 4; ++r) {
      int idx = tid + 256 * r;
      int kk = idx >> 6, cc = idx & 63;
      const float* row = Xb + (size_t)(k0 + kk) * IN_;
      Xi[kk][cc] = row[i0 + cc];
      Xj[kk][cc] = row[j0 + cc];
    }
    __syncthreads();
#pragma unroll
    for (int kk = 0; kk < 16; ++kk) {
      float a[4], bb[4];
#pragma unroll
      for (int u = 0; u < 4; ++u) a[u] = Xi[kk][ty * 4 + u];
#pragma unroll
      for (int u = 0; u < 4; ++u) bb[u] = Xj[kk][tx * 4 + u];
#pragma unroll
      for (int u = 0; u < 4; ++u)
#pragma unroll
        for (int w = 0; w < 4; ++w) acc[u][w] += a[u] * bb[w];
    }
    if (diag && tid < 64) {
#pragma unroll
      for (int kk = 0; kk < 16; ++kk) ssum += Xi[kk][tid];
    }
    __syncthreads();
  }
  float* Gb = G + (size_t)b * IN_ * IN_;
#pragma unroll
  for (int u = 0; u < 4; ++u)
#pragma unroll
    for (int w = 0; w < 4; ++w) {
      int gi = i0 + ty * 4 + u, gj = j0 + tx * 4 + w;
      Gb[(size_t)gi * IN_ + gj] = acc[u][w];
      if (!diag) Gb[(size_t)gj * IN_ + gi] = acc[u][w];
    }
  if (diag && tid < 64) svec[b * IN_ + i0 + tid] = ssum;
}

__global__ __launch_bounds__(256) void k_aall(const float* __restrict__ Wq,
                                              const float* __restrict__ G,
                                              float* __restrict__ Aall) {
  const int jt = blockIdx.x;
  const int h = blockIdx.y, b = blockIdx.z;
  __shared__ float Ws[16][64];
  __shared__ float Gs[16][64];
  const float* Gb = G + (size_t)b * IN_ * IN_;
  const int tx = threadIdx.x, ty = threadIdx.y;
  const int tid = ty * 16 + tx;
  float acc[4][4] = {};
  for (int c0 = 0; c0 < IN_; c0 += 16) {
#pragma unroll
    for (int r = 0; r < 4; ++r) {
      int idx = tid + 256 * r;
      int kk = idx >> 6, cc = idx & 63;
      Ws[kk][cc] = Wq[(size_t)(c0 + kk) * HD_ + h * D_ + cc];
      Gs[kk][cc] = Gb[(size_t)(c0 + kk) * IN_ + jt * 64 + cc];
    }
    __syncthreads();
#pragma unroll
    for (int kk = 0; kk < 16; ++kk) {
      float a[4], bb[4];
#pragma unroll
      for (int u = 0; u < 4; ++u) a[u] = Ws[kk][ty * 4 + u];
#pragma unroll
      for (int u = 0; u < 4; ++u) bb[u] = Gs[kk][tx * 4 + u];
#pragma unroll
      for (int u = 0; u < 4; ++u)
#pragma unroll
        for (int w = 0; w < 4; ++w) acc[u][w] += a[u] * bb[w];
    }
    __syncthreads();
  }
  const int hb = h * B_ + b;
  float* Ahb = Aall + (size_t)hb * D_ * IN_;
#pragma unroll
  for (int u = 0; u < 4; ++u)
#pragma unroll
    for (int w = 0; w < 4; ++w)
      Ahb[(size_t)(ty * 4 + u) * IN_ + jt * 64 + tx * 4 + w] = acc[u][w];
}

__global__ __launch_bounds__(256) void k_attn_f32(
    const float* __restrict__ Wq, const float* __restrict__ Wk,
    const float* __restrict__ Wv, const float* __restrict__ Wp,
    const float* __restrict__ bq, const float* __restrict__ bk,
    const float* __restrict__ bv, const float* __restrict__ gamma,
    const float* __restrict__ Aall, const float* __restrict__ svec,
    float* __restrict__ Wfin, float* __restrict__ bfin) {
  const int h = blockIdx.x, b = blockIdx.y;
  const int hb = h * B_ + b;
  const int tx = threadIdx.x, ty = threadIdx.y;
  const int tid = ty * 16 + tx;
  __shared__ float Ast[64][17];
  __shared__ float Ws[16][64];
  __shared__ float Esh[64][65];
  __shared__ float t1[64], t2[64];
  const float* Ahb = Aall + (size_t)hb * D_ * IN_;
  if (tid < 64) {
    float a2 = 0.f;
    for (int c = 0; c < IN_; ++c)
      a2 += svec[b * IN_ + c] * Wk[(size_t)c * HD_ + h * D_ + tid];
    t1[tid] = a2;
  } else if (tid < 128) {
    int d = tid - 64;
    float a2 = 0.f;
    for (int c = 0; c < IN_; ++c)
      a2 += svec[b * IN_ + c] * Wq[(size_t)c * HD_ + h * D_ + d];
    t2[d] = a2;
  }
  float acc[4][4] = {};
  for (int c0 = 0; c0 < IN_; c0 += 16) {
#pragma unroll
    for (int r = 0; r < 4; ++r) {
      int idx = tid + 256 * r;
      int dd = idx >> 4, kk = idx & 15;
      Ast[dd][kk] = Ahb[(size_t)dd * IN_ + c0 + kk];
      int kk2 = idx >> 6, ee = idx & 63;
      Ws[kk2][ee] = Wk[(size_t)(c0 + kk2) * HD_ + h * D_ + ee];
    }
    __syncthreads();
#pragma unroll
    for (int kk = 0; kk < 16; ++kk) {
      float a[4], bb[4];
#pragma unroll
      for (int u = 0; u < 4; ++u) a[u] = Ast[ty * 4 + u][kk];
#pragma unroll
      for (int u = 0; u < 4; ++u) bb[u] = Ws[kk][tx * 4 + u];
#pragma unroll
      for (int u = 0; u < 4; ++u)
#pragma unroll
        for (int w = 0; w < 4; ++w) acc[u][w] += a[u] * bb[w];
    }
    __syncthreads();
  }
#pragma unroll
  for (int u = 0; u < 4; ++u) {
    int d = ty * 4 + u;
    float bqd = bq[h * D_ + d];
    float t2d = t2[d];
#pragma unroll
    for (int w = 0; w < 4; ++w) {
      int e = tx * 4 + w;
      float bke = bk[h * D_ + e];
      Esh[d][e] = acc[u][w] + bqd * t1[e] + t2d * bke + (float)K_ * bqd * bke;
    }
  }
  __syncthreads();
  if (tid < 64) {
    float m = -1e30f;
    for (int e = 0; e < 64; ++e) m = fmaxf(m, Esh[tid][e]);
    float ssum = 0.f;
    for (int e = 0; e < 64; ++e) {
      float p = __expf(Esh[tid][e] - m);
      Esh[tid][e] = p;
      ssum += p;
    }
    float inv = 1.f / ssum;
    for (int e = 0; e < 64; ++e) Esh[tid][e] *= inv;
  }
  __syncthreads();
  const float g = gamma[h];
  const float inv1g = 1.f / (1.f + g);
  if (tid < 64) {
    float a2 = 0.f;
    for (int e = 0; e < 64; ++e) a2 += bv[h * D_ + e] * Esh[tid][e];
    bfin[hb * D_ + tid] = g * a2 * inv1g;
  }
  float* Wf = Wfin + (size_t)hb * IN_ * D_;
  for (int it2 = 0; it2 < 128; ++it2) {
    int idx = tid + 256 * it2;
    int c = idx >> 6, q = idx & 63;
    const float* Wvr = Wv + (size_t)c * HD_ + h * D_;
    float a2 = 0.f;
#pragma unroll
    for (int e = 0; e < 64; ++e) a2 += Wvr[e] * Esh[q][e];
    Wf[idx] = (g * a2 + Wp[(size_t)c * D_ + q]) * inv1g;
  }
}

__global__ __launch_bounds__(256) void k_out_f32(const float* __restrict__ y,
                                                 const float* __restrict__ Wfin,
                                                 const float* __restrict__ bfin,
                                                 float* __restrict__ out) {
  const int kt = blockIdx.x;
  const int hb = blockIdx.y;
  const int h = hb >> 3, b = hb & 7;
  __shared__ float Ys[64][17];
  __shared__ float Ws[16][64];
  const int tx = threadIdx.x, ty = threadIdx.y;
  const int tid = ty * 16 + tx;
  const float* Yb = y + (size_t)b * K_ * IN_;
  const float* Wf = Wfin + (size_t)hb * IN_ * D_;
  const int k0 = kt * 64;
  float acc[4][4] = {};
  for (int c0 = 0; c0 < IN_; c0 += 16) {
#pragma unroll
    for (int r = 0; r < 4; ++r) {
      int idx = tid + 256 * r;
      int rr = idx >> 4, kk = idx & 15;
      Ys[rr][kk] = Yb[(size_t)(k0 + rr) * IN_ + c0 + kk];
      int kk2 = idx >> 6, qq = idx & 63;
      Ws[kk2][qq] = Wf[(size_t)(c0 + kk2) * D_ + qq];
    }
    __syncthreads();
#pragma unroll
    for (int kk = 0; kk < 16; ++kk) {
      float a[4], bb[4];
#pragma unroll
      for (int u = 0; u < 4; ++u) a[u] = Ys[ty * 4 + u][kk];
#pragma unroll
      for (int u = 0; u < 4; ++u) bb[u] = Ws[kk][tx * 4 + u];
#pragma unroll
      for (int u = 0; u < 4; ++u)
#pragma unroll
        for (int w = 0; w < 4; ++w) acc[u][w] += a[u] * bb[w];
    }
    __syncthreads();
  }
  float* ob = out + (((size_t)b * H_ + h) * K_ + k0) * D_;
#pragma unroll
  for (int u = 0; u < 4; ++u) {
    int k = ty * 4 + u;
#pragma unroll
    for (int w = 0; w < 4; ++w) {
      int q = tx * 4 + w;
      ob[(size_t)k * D_ + q] = acc[u][w] + bfin[hb * D_ + q];
    }
  }
}

// =========================================================================
extern "C" void kernel_launch(void* const* d_in, const int* in_sizes, int n_in,
                              void* d_out, int out_size, void* d_ws,
                              size_t ws_size, hipStream_t stream) {
  const float* x = (const float*)d_in[0];
  const float* y = (const float*)d_in[1];
  const float* Wq = (const float*)d_in[2];
  const float* bq = (const float*)d_in[3];
  const float* Wk = (const float*)d_in[4];
  const float* bk = (const float*)d_in[5];
  const float* Wv = (const float*)d_in[6];
  const float* bv = (const float*)d_in[7];
  const float* Wp = (const float*)d_in[8];
  const float* gm = (const float*)d_in[9];
  float* out = (float*)d_out;

  const size_t NEED = 86016000;
  if (ws_size >= NEED) {
    char* w = (char*)d_ws;
    u16* xt_hi = (u16*)(w);           // phase 1
    u16* Ahi = (u16*)(w);             // phase 2 aliases
    u16* Alo = (u16*)(w + 4194304);
    u16* Wft = (u16*)(w + 8388608);
    u16* xt_lo = (u16*)(w + 33554432);
    u16* yb = (u16*)(w + 33554432);   // phase 2 alias of xt_lo
    float* G = (float*)(w + 67108864);
    u16* Ghi = (u16*)(w + 75497472);
    u16* Glo = (u16*)(w + 79691776);
    u16* Wqt_hi = (u16*)(w + 83886080);
    u16* Wqt_lo = (u16*)(w + 84410368);
    u16* Wkt_hi = (u16*)(w + 84934656);
    u16* Wkt_lo = (u16*)(w + 85458944);
    float* bfin = (float*)(w + 85983232);
    float* svec = (float*)(w + 85999616);

    hipMemsetAsync(G, 0, 8388608, stream);
    hipMemsetAsync(svec, 0, 16384, stream);
    k_cvt_w<<<dim3(8, 8, 2), 256, 0, stream>>>(Wq, Wk, Wqt_hi, Wqt_lo, Wkt_hi,
                                               Wkt_lo);
    k_cvt_x<<<dim3(64, 8, 8), 256, 0, stream>>>(x, xt_hi, xt_lo, svec);
    k_gram_mfma<<<dim3(192), 512, 0, stream>>>(xt_hi, xt_lo, G);
    k_cvt_y<<<dim3(8192), 256, 0, stream>>>(y, yb);
    k_cvt_g<<<dim3(8, 8, 8), 256, 0, stream>>>(G, Ghi, Glo);
    k_aall_mfma<<<dim3(8, 64), 256, 0, stream>>>(Wqt_hi, Wqt_lo, Ghi, Glo, Ahi,
                                                 Alo);
    k_attn3<<<dim3(8, 8), 256, 0, stream>>>(Ahi, Alo, Wqt_hi, Wqt_lo, Wkt_hi,
                                            Wkt_lo, Wv, Wp, bq, bk, bv, gm,
                                            svec, Wft, bfin);
    k_out_mfma<<<dim3(16, 32), 256, 0, stream>>>(yb, Wft, bfin, out);
  } else {
    float* ws = (float*)d_ws;
    float* G = ws;
    float* Aall = ws + 2097152;
    float* Wfin = ws + 4194304;
    float* bfin = ws + 6291456;
    float* svec = ws + 6295552;
    dim3 blk(16, 16);
    k_gram<<<dim3(8, 8, 8), blk, 0, stream>>>(x, G, svec);
    k_aall<<<dim3(8, 8, 8), blk, 0, stream>>>(Wq, G, Aall);
    k_attn_f32<<<dim3(8, 8), blk, 0, stream>>>(Wq, Wk, Wv, Wp, bq, bk, bv, gm,
                                               Aall, svec, Wfin, bfin);
    k_out_f32<<<dim3(64, 64), blk, 0, stream>>>(y, Wfin, bfin, out);
  }
}

// Round 8
// 323.141 us; speedup vs baseline: 1.0796x; 1.0796x over previous
//
#include <hip/hip_runtime.h>

#define B_ 8
#define K_ 4096
#define IN_ 512
#define H_ 8
#define D_ 64
#define HD_ 512  // H_*D_

typedef short bf16x8 __attribute__((ext_vector_type(8)));
typedef float f32x4 __attribute__((ext_vector_type(4)));
typedef unsigned short u16;
typedef unsigned short us8v __attribute__((ext_vector_type(8)));
typedef unsigned short us4v __attribute__((ext_vector_type(4)));

__device__ inline u16 f2bf_rn(float f) {
  unsigned u = __float_as_uint(f);
  u += 0x7fffu + ((u >> 16) & 1u);
  return (u16)(u >> 16);
}
__device__ inline float bf2f(u16 h) {
  return __uint_as_float(((unsigned)h) << 16);
}

// async global->LDS, 16B per lane. LDS dest is wave-uniform base + lane*16.
__device__ inline void gl_lds16(const u16* g, u16* l) {
  __builtin_amdgcn_global_load_lds(
      (const __attribute__((address_space(1))) unsigned int*)g,
      (__attribute__((address_space(3))) unsigned int*)l, 16, 0, 0);
}

// =========================================================================
// ws layout (bytes), fast path:
//   region0 [0, 33554432):
//     phase1: xt_hi [B][IN][K] bf16 (32MB)
//     phase2 (after k_gram): Ahi @0 (4MB), Alo @4MB, Wft @8MB (4MB)
//   xt_lo  @33554432  (32MB)   -- phase2: yb (y as bf16, 32MB)
//   G      @67108864  [B][IN][IN] f32 (8MB) -- after k_cvt_g: Pbf (512KB)
//   Ghi    @75497472 (4MB)   Glo @79691776 (4MB)
//   Wqt_hi @83886080 (512KB) Wqt_lo @84410368
//   Wkt_hi @84934656         Wkt_lo @85458944
//   bfin   @85983232 (16KB)  svec @85999616 (16KB)
//   NEED = 86016000
// =========================================================================

// x (B,K,IN) f32 -> xt_hi/xt_lo (B,IN,K) bf16 split, + column sums (atomic)
__global__ __launch_bounds__(256) void k_cvt_x(const float* __restrict__ x,
                                               u16* __restrict__ xt_hi,
                                               u16* __restrict__ xt_lo,
                                               float* __restrict__ svec) {
  const int kt = blockIdx.x, ct = blockIdx.y, b = blockIdx.z;
  __shared__ float Xs[64][65];
  const int tid = threadIdx.x;
  const float* src = x + ((size_t)b * K_ + kt * 64) * IN_ + ct * 64;
#pragma unroll
  for (int r = 0; r < 4; ++r) {
    int idx = tid + 256 * r;  // 0..1023
    int k = idx >> 4, c4 = (idx & 15) * 4;
    f32x4 v = *(const f32x4*)(src + (size_t)k * IN_ + c4);
    Xs[k][c4 + 0] = v[0];
    Xs[k][c4 + 1] = v[1];
    Xs[k][c4 + 2] = v[2];
    Xs[k][c4 + 3] = v[3];
  }
  __syncthreads();
  if (tid < 64) {
    float s = 0.f;
#pragma unroll
    for (int k = 0; k < 64; ++k) s += Xs[k][tid];
    atomicAdd(&svec[b * IN_ + ct * 64 + tid], s);
  }
#pragma unroll
  for (int r = 0; r < 2; ++r) {
    int idx = tid + 256 * r;  // 0..511
    int c = idx >> 3, ck = (idx & 7) * 8;
    us8v hv, lv;
#pragma unroll
    for (int j = 0; j < 8; ++j) {
      float f = Xs[ck + j][c];
      u16 h = f2bf_rn(f);
      float lo = f - bf2f(h);
      hv[j] = h;
      lv[j] = f2bf_rn(lo);
    }
    size_t off = ((size_t)(b * IN_ + ct * 64 + c)) * K_ + kt * 64 + ck;
    *(us8v*)(xt_hi + off) = hv;
    *(us8v*)(xt_lo + off) = lv;
  }
}

// y (B,K,IN) f32 -> yb bf16 (same layout). Runs after k_gram frees xt_lo.
__global__ __launch_bounds__(256) void k_cvt_y(const float* __restrict__ y,
                                               u16* __restrict__ yb) {
  size_t i = ((size_t)blockIdx.x * 256 + threadIdx.x) * 8;
  f32x4 v0 = *(const f32x4*)(y + i);
  f32x4 v1 = *(const f32x4*)(y + i + 4);
  us8v o;
  o[0] = f2bf_rn(v0[0]); o[1] = f2bf_rn(v0[1]);
  o[2] = f2bf_rn(v0[2]); o[3] = f2bf_rn(v0[3]);
  o[4] = f2bf_rn(v1[0]); o[5] = f2bf_rn(v1[1]);
  o[6] = f2bf_rn(v1[2]); o[7] = f2bf_rn(v1[3]);
  *(us8v*)(yb + i) = o;
}

// Wq/Wk (512x512) -> transposed bf16 hi/lo: Wt[dcol][c] = W[c][dcol]
__global__ __launch_bounds__(256) void k_cvt_w(
    const float* __restrict__ Wq, const float* __restrict__ Wk,
    u16* __restrict__ Wqt_hi, u16* __restrict__ Wqt_lo,
    u16* __restrict__ Wkt_hi, u16* __restrict__ Wkt_lo) {
  const int ti = blockIdx.x, tj = blockIdx.y;
  const float* src = blockIdx.z ? Wk : Wq;
  u16* dhi = blockIdx.z ? Wkt_hi : Wqt_hi;
  u16* dlo = blockIdx.z ? Wkt_lo : Wqt_lo;
  __shared__ float T[64][65];
  const int tid = threadIdx.x;
#pragma unroll
  for (int r = 0; r < 4; ++r) {
    int idx = tid + 256 * r;
    int rr = idx >> 4, c4 = (idx & 15) * 4;
    f32x4 v = *(const f32x4*)(src + (size_t)(tj * 64 + rr) * 512 + ti * 64 + c4);
    T[rr][c4 + 0] = v[0]; T[rr][c4 + 1] = v[1];
    T[rr][c4 + 2] = v[2]; T[rr][c4 + 3] = v[3];
  }
  __syncthreads();
#pragma unroll
  for (int r = 0; r < 2; ++r) {
    int idx = tid + 256 * r;
    int d = idx >> 3, ck = (idx & 7) * 8;
    us8v hv, lv;
#pragma unroll
    for (int j = 0; j < 8; ++j) {
      float f = T[ck + j][d];
      u16 h = f2bf_rn(f);
      hv[j] = h;
      lv[j] = f2bf_rn(f - bf2f(h));
    }
    size_t off = (size_t)(ti * 64 + d) * 512 + tj * 64 + ck;
    *(us8v*)(dhi + off) = hv;
    *(us8v*)(dlo + off) = lv;
  }
}

#define GP 72  // padded LDS row (64 bf16 + 8) = 144 B (used by k_attn3)

// G_b += X^T X: 128x128 block tile, 2x2 waves of 64x64, bf16x3, split-K x8.
// R6 structure (best measured: 53.5 us): counted-vmcnt pipeline (T4):
// STAGE(t+1) -> vmcnt(L) (own tile-t DMA only, never 0 mid-loop) -> raw
// s_barrier -> ds_read+MFMA -> raw s_barrier. Conflict-free both-sides
// swizzle: 16B slot ^ ((row>>1)&3). [R7 256^2-tile variant REVERTED:
// 192 blocks = 0.75/CU left 25% CUs idle + no inter-block overlap -> 79us.]
__global__ __launch_bounds__(256, 2) void k_gram_mfma(
    const u16* __restrict__ xt_hi, const u16* __restrict__ xt_lo,
    float* __restrict__ G) {
  const int fid = blockIdx.x;     // 0..639
  const int kc = fid & 7;         // XCD-affine
  const int slot = fid >> 3;      // 0..79
  const int b = slot / 10;
  int pp = slot - b * 10, ti = 0;
  while (pp >= 4 - ti) { pp -= 4 - ti; ++ti; }
  const int tj = ti + pp;
  const bool diag = (ti == tj);
  // [buf][array(ih,il,jh,jl)][128 rows][32 cols] bf16 -> 2 x 32KB
  __shared__ u16 P[2][4 * 128 * 32];
  const int tid = threadIdx.x;
  const int wave = tid >> 6, lane = tid & 63;
  const int wm = wave & 1, wn = wave >> 1;
  const int m16 = lane & 15, quad = lane >> 4;
  const size_t base_i = ((size_t)(b * IN_ + ti * 128)) * K_;
  const size_t base_j = ((size_t)(b * IN_ + tj * 128)) * K_;
  const int sr = lane >> 2, sslot = lane & 3;  // staging: 16 rows x 4 slots
  const int boff_h = diag ? 0 : 2 * 4096;
  const int boff_l = diag ? 4096 : 3 * 4096;

  f32x4 zf = {0.f, 0.f, 0.f, 0.f};
  f32x4 acc[4][4];
#pragma unroll
  for (int mt = 0; mt < 4; ++mt)
#pragma unroll
    for (int nt = 0; nt < 4; ++nt) acc[mt][nt] = zf;
  const int kbeg = kc * 512;

  auto STAGE = [&](int t, int buf) {
    const int k0 = kbeg + t * 32;
    u16* Pb = &P[buf][0];
#pragma unroll
    for (int g = 0; g < 2; ++g) {
      int rbase = wave * 32 + g * 16;           // wave-uniform, mult of 16
      int r = rbase + sr;                       // per-lane row
      size_t go = (size_t)r * K_ + k0 + ((sslot ^ ((sr >> 1) & 3)) << 3);
      int lo = rbase * 32;                      // wave-uniform LDS base
      gl_lds16(xt_hi + base_i + go, Pb + 0 * 4096 + lo);
      gl_lds16(xt_lo + base_i + go, Pb + 1 * 4096 + lo);
      if (!diag) {
        gl_lds16(xt_hi + base_j + go, Pb + 2 * 4096 + lo);
        gl_lds16(xt_lo + base_j + go, Pb + 3 * 4096 + lo);
      }
    }
  };

  STAGE(0, 0);
  int cur = 0;
  const int ac = ((quad ^ ((m16 >> 1) & 3)) << 3);  // conflict-free swizzle
  for (int t = 0; t < 16; ++t) {
    if (t < 15) {
      STAGE(t + 1, cur ^ 1);
      // drain own tile-t DMA only; tile t+1's loads stay in flight
      if (diag) asm volatile("s_waitcnt vmcnt(4)" ::: "memory");
      else      asm volatile("s_waitcnt vmcnt(8)" ::: "memory");
    } else {
      asm volatile("s_waitcnt vmcnt(0)" ::: "memory");
    }
    __builtin_amdgcn_s_barrier();  // all waves' tile-t DMA visible
    __builtin_amdgcn_sched_barrier(0);
    const u16* Pb = &P[cur][0];
    bf16x8 ah[4], al[4], bh[4], bl[4];
#pragma unroll
    for (int tt = 0; tt < 4; ++tt) {
      int ar = (wm * 64 + tt * 16 + m16) * 32 + ac;
      ah[tt] = *(const bf16x8*)(Pb + ar);
      al[tt] = *(const bf16x8*)(Pb + 4096 + ar);
      int br = (wn * 64 + tt * 16 + m16) * 32 + ac;
      bh[tt] = *(const bf16x8*)(Pb + boff_h + br);
      bl[tt] = *(const bf16x8*)(Pb + boff_l + br);
    }
#pragma unroll
    for (int mt = 0; mt < 4; ++mt)
#pragma unroll
      for (int nt = 0; nt < 4; ++nt) {
        acc[mt][nt] = __builtin_amdgcn_mfma_f32_16x16x32_bf16(
            ah[mt], bh[nt], acc[mt][nt], 0, 0, 0);
        acc[mt][nt] = __builtin_amdgcn_mfma_f32_16x16x32_bf16(
            ah[mt], bl[nt], acc[mt][nt], 0, 0, 0);
        acc[mt][nt] = __builtin_amdgcn_mfma_f32_16x16x32_bf16(
            al[mt], bh[nt], acc[mt][nt], 0, 0, 0);
      }
    __builtin_amdgcn_s_barrier();  // readers done before buf re-staged
    cur ^= 1;
  }
  float* Gb = G + (size_t)b * IN_ * IN_;
#pragma unroll
  for (int mt = 0; mt < 4; ++mt)
#pragma unroll
    for (int nt = 0; nt < 4; ++nt)
#pragma unroll
      for (int r = 0; r < 4; ++r) {
        int gi = ti * 128 + wm * 64 + mt * 16 + quad * 4 + r;
        int gj = tj * 128 + wn * 64 + nt * 16 + m16;
        atomicAdd(&Gb[(size_t)gi * IN_ + gj], acc[mt][nt][r]);
      }
}

// G f32 (upper 64-tiles) -> Ghi/Glo bf16, mirroring lower tiles
__global__ __launch_bounds__(256) void k_cvt_g(const float* __restrict__ G,
                                               u16* __restrict__ Ghi,
                                               u16* __restrict__ Glo) {
  const int ti = blockIdx.x, tj = blockIdx.y, b = blockIdx.z;
  if (tj < ti) return;
  const float* Gb = G + (size_t)b * IN_ * IN_;
  u16* ghb = Ghi + (size_t)b * IN_ * IN_;
  u16* glb = Glo + (size_t)b * IN_ * IN_;
  __shared__ float T[64][65];
  const int tid = threadIdx.x;
#pragma unroll
  for (int r = 0; r < 4; ++r) {
    int idx = tid + 256 * r;
    int rr = idx >> 4, c4 = (idx & 15) * 4;
    f32x4 v = *(const f32x4*)(Gb + (size_t)(ti * 64 + rr) * IN_ + tj * 64 + c4);
    T[rr][c4 + 0] = v[0]; T[rr][c4 + 1] = v[1];
    T[rr][c4 + 2] = v[2]; T[rr][c4 + 3] = v[3];
  }
  __syncthreads();
#pragma unroll
  for (int r = 0; r < 2; ++r) {
    int idx = tid + 256 * r;
    int rr = idx >> 3, ck = (idx & 7) * 8;
    us8v hv, lv;
#pragma unroll
    for (int j = 0; j < 8; ++j) {
      float f = T[rr][ck + j];
      u16 h = f2bf_rn(f);
      hv[j] = h;
      lv[j] = f2bf_rn(f - bf2f(h));
    }
    size_t off = (size_t)(ti * 64 + rr) * IN_ + tj * 64 + ck;
    *(us8v*)(ghb + off) = hv;
    *(us8v*)(glb + off) = lv;
  }
  if (ti != tj) {
#pragma unroll
    for (int r = 0; r < 2; ++r) {
      int idx = tid + 256 * r;
      int rr = idx >> 3, ck = (idx & 7) * 8;
      us8v hv, lv;
#pragma unroll
      for (int j = 0; j < 8; ++j) {
        float f = T[ck + j][rr];  // mirrored element
        u16 h = f2bf_rn(f);
        hv[j] = h;
        lv[j] = f2bf_rn(f - bf2f(h));
      }
      size_t off = (size_t)(tj * 64 + rr) * IN_ + ti * 64 + ck;
      *(us8v*)(ghb + off) = hv;
      *(us8v*)(glb + off) = lv;
    }
  }
}

// A[hb] = Wqt_h (64x512) @ G_b (512x512), 3-product MFMA. bf16 hi/lo out.
// m97-style gload_lds staging + both-sides XOR swizzle.
__global__ __launch_bounds__(256) void k_aall_mfma(
    const u16* __restrict__ Wqt_hi, const u16* __restrict__ Wqt_lo,
    const u16* __restrict__ Ghi, const u16* __restrict__ Glo,
    u16* __restrict__ Ahi, u16* __restrict__ Alo) {
  const int ct = blockIdx.x;  // c' tile 0..7
  const int hb = blockIdx.y;  // h*8+b
  const int h = hb >> 3, b = hb & 7;
  __shared__ u16 S[4 * 64 * 64];  // Ah | Al | Bh | Bl, 32KB (epilogue reuses)
  u16* Ah = S;
  u16* Al = S + 64 * 64;
  u16* Bh = S + 2 * 64 * 64;
  u16* Bl = S + 3 * 64 * 64;
  const int tid = threadIdx.x;
  const int wave = tid >> 6, lane = tid & 63;
  const int m16 = lane & 15, quad = lane >> 4;
  const u16* Abase_h = Wqt_hi + (size_t)(h * 64) * IN_;
  const u16* Abase_l = Wqt_lo + (size_t)(h * 64) * IN_;
  const u16* Bbase_h = Ghi + (size_t)b * IN_ * IN_ + (size_t)(ct * 64) * IN_;
  const u16* Bbase_l = Glo + (size_t)b * IN_ * IN_ + (size_t)(ct * 64) * IN_;
  const int lrow = lane >> 3;
  const int lcol = ((lane & 7) * 8) ^ (lrow << 3);
  const size_t loff = (size_t)lrow * IN_ + lcol;
  f32x4 zf = {0.f, 0.f, 0.f, 0.f};
  f32x4 acc[4] = {zf, zf, zf, zf};
  for (int k0 = 0; k0 < IN_; k0 += 64) {
    __syncthreads();
#pragma unroll
    for (int r = 0; r < 2; ++r) {
      int rg = wave * 2 + r;  // 0..7
      size_t go = (size_t)(rg * 8) * IN_ + k0 + loff;
      int lo = rg * 8 * 64;
      gl_lds16(Abase_h + go, &Ah[lo]);
      gl_lds16(Abase_l + go, &Al[lo]);
      gl_lds16(Bbase_h + go, &Bh[lo]);
      gl_lds16(Bbase_l + go, &Bl[lo]);
    }
    __syncthreads();
#pragma unroll
    for (int kk = 0; kk < 64; kk += 32) {
      const int ac = (kk + quad * 8) ^ ((m16 & 7) << 3);
      int arow = (wave * 16 + m16) * 64 + ac;
      bf16x8 ah = *(const bf16x8*)&Ah[arow];
      bf16x8 al = *(const bf16x8*)&Al[arow];
#pragma unroll
      for (int n = 0; n < 4; ++n) {
        int brow = (n * 16 + m16) * 64 + ac;
        bf16x8 bh = *(const bf16x8*)&Bh[brow];
        bf16x8 bl = *(const bf16x8*)&Bl[brow];
        acc[n] = __builtin_amdgcn_mfma_f32_16x16x32_bf16(ah, bh, acc[n], 0, 0, 0);
        acc[n] = __builtin_amdgcn_mfma_f32_16x16x32_bf16(ah, bl, acc[n], 0, 0, 0);
        acc[n] = __builtin_amdgcn_mfma_f32_16x16x32_bf16(al, bh, acc[n], 0, 0, 0);
      }
    }
  }
  __syncthreads();
  float* Sf = (float*)S;  // 64*68*4 = 17408 B <= 32KB
#pragma unroll
  for (int n = 0; n < 4; ++n)
#pragma unroll
    for (int r = 0; r < 4; ++r) {
      int d = wave * 16 + quad * 4 + r;
      int cc = n * 16 + m16;
      Sf[d * 68 + cc] = acc[n][r];
    }
  __syncthreads();
#pragma unroll
  for (int r = 0; r < 2; ++r) {
    int idx = tid + 256 * r;
    int d = idx >> 3, ck = (idx & 7) * 8;
    us8v hv, lv;
#pragma unroll
    for (int j = 0; j < 8; ++j) {
      float f = Sf[d * 68 + ck + j];
      u16 h2 = f2bf_rn(f);
      hv[j] = h2;
      lv[j] = f2bf_rn(f - bf2f(h2));
    }
    size_t off = ((size_t)hb * 64 + d) * IN_ + ct * 64 + ck;
    *(us8v*)(Ahi + off) = hv;
    *(us8v*)(Alo + off) = lv;
  }
}

// per (h,b): E = A @ Wk (MFMA 3-product) + bias, softmax, bfin.
// Writes rounded attention probs Pbf[hb][q][e] bf16 (identical bits to the
// old in-kernel bfr) for k_wft, which now runs at 4x the parallelism.
__global__ __launch_bounds__(256) void k_attn3(
    const u16* __restrict__ Ahi, const u16* __restrict__ Alo,
    const u16* __restrict__ Wqt_hi, const u16* __restrict__ Wqt_lo,
    const u16* __restrict__ Wkt_hi, const u16* __restrict__ Wkt_lo,
    const float* __restrict__ bq, const float* __restrict__ bk,
    const float* __restrict__ bv, const float* __restrict__ gamma,
    const float* __restrict__ svec, u16* __restrict__ Pbf,
    float* __restrict__ bfin) {
  const int h = blockIdx.x, b = blockIdx.y;
  const int hb = h * B_ + b;
  const int tid = threadIdx.x;
  const int wave = tid >> 6, lane = tid & 63;
  const int m16 = lane & 15, quad = lane >> 4;
  __shared__ u16 S[4 * 64 * GP];
  __shared__ float Esh[64][65];
  __shared__ float t1[64], t2[64];
  u16* Ah = S;
  u16* Al = S + 64 * GP;
  u16* Bh = S + 2 * 64 * GP;
  u16* Bl = S + 3 * 64 * GP;

  if (tid < 64) {
    float s = 0.f;
    const u16* wh = Wkt_hi + (size_t)(h * 64 + tid) * IN_;
    const u16* wl = Wkt_lo + (size_t)(h * 64 + tid) * IN_;
    const float* sv = svec + b * IN_;
    for (int c = 0; c < IN_; c += 8) {
      us8v hv = *(const us8v*)(wh + c);
      us8v lv = *(const us8v*)(wl + c);
#pragma unroll
      for (int j = 0; j < 8; ++j)
        s += sv[c + j] * (bf2f(hv[j]) + bf2f(lv[j]));
    }
    t1[tid] = s;
  } else if (tid < 128) {
    int d = tid - 64;
    float s = 0.f;
    const u16* wh = Wqt_hi + (size_t)(h * 64 + d) * IN_;
    const u16* wl = Wqt_lo + (size_t)(h * 64 + d) * IN_;
    const float* sv = svec + b * IN_;
    for (int c = 0; c < IN_; c += 8) {
      us8v hv = *(const us8v*)(wh + c);
      us8v lv = *(const us8v*)(wl + c);
#pragma unroll
      for (int j = 0; j < 8; ++j)
        s += sv[c + j] * (bf2f(hv[j]) + bf2f(lv[j]));
    }
    t2[d] = s;
  }

  const u16* Abase_h = Ahi + (size_t)hb * 64 * IN_;
  const u16* Abase_l = Alo + (size_t)hb * 64 * IN_;
  const u16* Bbase_h = Wkt_hi + (size_t)(h * 64) * IN_;
  const u16* Bbase_l = Wkt_lo + (size_t)(h * 64) * IN_;
  f32x4 zf = {0.f, 0.f, 0.f, 0.f};
  f32x4 acc[4] = {zf, zf, zf, zf};
  for (int k0 = 0; k0 < IN_; k0 += 64) {
    __syncthreads();
#pragma unroll
    for (int r = 0; r < 2; ++r) {
      int idx = tid + 256 * r;
      int row = idx >> 3, ck = (idx & 7) * 8;
      int lo = row * GP + ck;
      *(us8v*)&Ah[lo] = *(const us8v*)(Abase_h + (size_t)row * IN_ + k0 + ck);
      *(us8v*)&Al[lo] = *(const us8v*)(Abase_l + (size_t)row * IN_ + k0 + ck);
      *(us8v*)&Bh[lo] = *(const us8v*)(Bbase_h + (size_t)row * IN_ + k0 + ck);
      *(us8v*)&Bl[lo] = *(const us8v*)(Bbase_l + (size_t)row * IN_ + k0 + ck);
    }
    __syncthreads();
#pragma unroll
    for (int kk = 0; kk < 64; kk += 32) {
      int arow = (wave * 16 + m16) * GP + kk + quad * 8;
      bf16x8 ah = *(const bf16x8*)&Ah[arow];
      bf16x8 al = *(const bf16x8*)&Al[arow];
#pragma unroll
      for (int n = 0; n < 4; ++n) {
        int brow = (n * 16 + m16) * GP + kk + quad * 8;
        bf16x8 bh = *(const bf16x8*)&Bh[brow];
        bf16x8 bl = *(const bf16x8*)&Bl[brow];
        acc[n] = __builtin_amdgcn_mfma_f32_16x16x32_bf16(ah, bh, acc[n], 0, 0, 0);
        acc[n] = __builtin_amdgcn_mfma_f32_16x16x32_bf16(ah, bl, acc[n], 0, 0, 0);
        acc[n] = __builtin_amdgcn_mfma_f32_16x16x32_bf16(al, bh, acc[n], 0, 0, 0);
      }
    }
  }
  __syncthreads();
#pragma unroll
  for (int n = 0; n < 4; ++n)
#pragma unroll
    for (int r = 0; r < 4; ++r) {
      int d = wave * 16 + quad * 4 + r;
      int e = n * 16 + m16;
      float bqd = bq[h * D_ + d], bke = bk[h * D_ + e];
      Esh[d][e] = acc[n][r] + bqd * t1[e] + t2[d] * bke + (float)K_ * bqd * bke;
    }
  __syncthreads();
  const float g = gamma[h];
  const float inv1g = 1.f / (1.f + g);
  if (tid < 64) {
    float m = -1e30f;
    for (int e = 0; e < 64; ++e) m = fmaxf(m, Esh[tid][e]);
    float ssum = 0.f;
    for (int e = 0; e < 64; ++e) {
      float p = __expf(Esh[tid][e] - m);
      Esh[tid][e] = p;
      ssum += p;
    }
    float inv = 1.f / ssum;
    float bsum = 0.f;
    for (int e = 0; e < 64; ++e) {
      Esh[tid][e] *= inv;
      bsum += bv[h * D_ + e] * Esh[tid][e];
    }
    bfin[hb * D_ + tid] = g * bsum * inv1g;
  }
  __syncthreads();

  // store rounded probs: Pbf[hb][q][e] bf16 (same f2bf_rn as the old bfr)
  {
    int q = tid >> 2, c0 = (tid & 3) * 16;
    us8v o1, o2;
#pragma unroll
    for (int j = 0; j < 8; ++j) {
      o1[j] = f2bf_rn(Esh[q][c0 + j]);
      o2[j] = f2bf_rn(Esh[q][c0 + 8 + j]);
    }
    u16* Pq = Pbf + (size_t)hb * 4096 + q * 64 + c0;
    *(us8v*)Pq = o1;
    *(us8v*)(Pq + 8) = o2;
  }
}

// Wft[q][c] = bf16((g * sum_e Wv[c,e]*attn[q,e] + Wp[c,q])/(1+g)) via MFMA.
// Split from k_attn3: grid (4 ct x 64 hb) = 256 blocks (old: 64 blocks,
// 25% machine occupancy). Same per-c MFMA chain / rounding -> identical bits.
__global__ __launch_bounds__(256) void k_wft(
    const u16* __restrict__ Pbf, const float* __restrict__ Wv,
    const float* __restrict__ Wp, const float* __restrict__ gamma,
    u16* __restrict__ Wft) {
  const int ct = blockIdx.x;   // 0..3 -> 128 c each
  const int hb = blockIdx.y;   // h*8+b
  const int h = hb >> 3;
  const int tid = threadIdx.x, wave = tid >> 6, lane = tid & 63;
  const int m16 = lane & 15, quad = lane >> 4;
  const float g = gamma[h];
  const float inv1g = 1.f / (1.f + g);
  f32x4 zf = {0.f, 0.f, 0.f, 0.f};

  // load P fragments (B-operand): bfr[n][kk], rows n*16+m16
  bf16x8 bfr[4][2];
  const u16* Pb = Pbf + (size_t)hb * 4096;
#pragma unroll
  for (int n = 0; n < 4; ++n)
#pragma unroll
    for (int kk = 0; kk < 2; ++kk)
      bfr[n][kk] =
          *(const bf16x8*)(Pb + (n * 16 + m16) * 64 + kk * 32 + quad * 8);

  u16* Wf = Wft + (size_t)hb * D_ * IN_;
#pragma unroll
  for (int mt = 0; mt < 2; ++mt) {
    f32x4 a4[4] = {zf, zf, zf, zf};
#pragma unroll
    for (int kk = 0; kk < 2; ++kk) {
      int c = ct * 128 + wave * 32 + mt * 16 + m16;
      const float* wv = Wv + (size_t)c * HD_ + h * D_ + kk * 32 + quad * 8;
      f32x4 v0 = *(const f32x4*)wv;
      f32x4 v1 = *(const f32x4*)(wv + 4);
      bf16x8 af;
      af[0] = f2bf_rn(v0[0]); af[1] = f2bf_rn(v0[1]);
      af[2] = f2bf_rn(v0[2]); af[3] = f2bf_rn(v0[3]);
      af[4] = f2bf_rn(v1[0]); af[5] = f2bf_rn(v1[1]);
      af[6] = f2bf_rn(v1[2]); af[7] = f2bf_rn(v1[3]);
#pragma unroll
      for (int n = 0; n < 4; ++n)
        a4[n] = __builtin_amdgcn_mfma_f32_16x16x32_bf16(af, bfr[n][kk], a4[n], 0, 0, 0);
    }
    int cb = ct * 128 + wave * 32 + mt * 16 + quad * 4;
#pragma unroll
    for (int n = 0; n < 4; ++n) {
      int q = n * 16 + m16;
      us4v st;
#pragma unroll
      for (int r = 0; r < 4; ++r) {
        float val = (g * a4[n][r] + Wp[(size_t)(cb + r) * D_ + q]) * inv1g;
        st[r] = f2bf_rn(val);
      }
      *(us4v*)(Wf + (size_t)q * IN_ + cb) = st;
    }
  }
}

// out = y @ Wft^T (+bfin), 2 heads/block, 256 rows/block, grid (16 kt, 32).
// 2-phase pipeline: reg-stage next Wft tile + next y frags during MFMA of
// current tile; double-buffered 16KB LDS, XOR-swizzled (col ^ ((row&7)<<3))
// so ds_read_b128 is conflict-optimal on 128B rows. y pre-converted to bf16
// (k_cvt_y) -> no in-loop cvt VALU, half the y bytes.
__global__ __launch_bounds__(256, 2) void k_out_mfma(
    const u16* __restrict__ yb, const u16* __restrict__ Wft,
    const float* __restrict__ bfin, float* __restrict__ out) {
  const int kt = blockIdx.x;
  const int b = blockIdx.y & 7, hq = blockIdx.y >> 3;  // hq 0..3
  const int h0 = hq * 2;
  __shared__ u16 Wsh[2][2 * 64 * 64];  // [buf][row*64+col], row=i*64+q, 16KB each
  const int tid = threadIdx.x, wave = tid >> 6, lane = tid & 63;
  const int m16 = lane & 15, quad = lane >> 4;
  const int swz = (m16 & 7) << 3;

  us8v stg[4];
  auto LOAD = [&](int c0) {
#pragma unroll
    for (int r = 0; r < 4; ++r) {
      int idx = tid + 256 * r;  // 0..1023
      int row = idx >> 3, ck = (idx & 7) * 8;
      int i = row >> 6, q = row & 63;
      const u16* src =
          Wft + ((size_t)((h0 + i) * 8 + b) * 64 + q) * IN_ + c0 + ck;
      stg[r] = *(const us8v*)src;
    }
  };
  auto WRITE = [&](int buf) {
#pragma unroll
    for (int r = 0; r < 4; ++r) {
      int idx = tid + 256 * r;
      int row = idx >> 3, ck = (idx & 7) * 8;
      *(us8v*)&Wsh[buf][row * 64 + (ck ^ ((row & 7) << 3))] = stg[r];
    }
  };
  bf16x8 yf[2][4];  // [kk][ms]
  auto LOADY = [&](bf16x8 (*yd)[4], int c0) {
#pragma unroll
    for (int kk = 0; kk < 2; ++kk)
#pragma unroll
      for (int ms = 0; ms < 4; ++ms) {
        int row = kt * 256 + wave * 64 + ms * 16 + m16;
        yd[kk][ms] = *(const bf16x8*)(yb + ((size_t)b * K_ + row) * IN_ + c0 +
                                      kk * 32 + quad * 8);
      }
  };

  f32x4 zf = {0.f, 0.f, 0.f, 0.f};
  f32x4 acc[4][2][4];  // [ms][i][nt]
#pragma unroll
  for (int ms = 0; ms < 4; ++ms)
#pragma unroll
    for (int i = 0; i < 2; ++i)
#pragma unroll
      for (int nt = 0; nt < 4; ++nt) acc[ms][i][nt] = zf;

  LOAD(0);
  LOADY(yf, 0);
  WRITE(0);
  __syncthreads();
  int cur = 0;
  for (int c0 = 0; c0 < IN_; c0 += 64) {
    const bool more = (c0 + 64 < IN_);
    bf16x8 yn[2][4];
    if (more) {
      LOAD(c0 + 64);
      LOADY(yn, c0 + 64);
    }
#pragma unroll
    for (int kk = 0; kk < 2; ++kk)
#pragma unroll
      for (int i = 0; i < 2; ++i)
#pragma unroll
        for (int nt = 0; nt < 4; ++nt) {
          int brow = i * 64 + nt * 16 + m16;
          bf16x8 bb = *(const bf16x8*)&Wsh[cur][brow * 64 +
                                               ((kk * 32 + quad * 8) ^ swz)];
#pragma unroll
          for (int ms = 0; ms < 4; ++ms)
            acc[ms][i][nt] = __builtin_amdgcn_mfma_f32_16x16x32_bf16(
                yf[kk][ms], bb, acc[ms][i][nt], 0, 0, 0);
        }
    if (more) {
      WRITE(cur ^ 1);
      __syncthreads();
      cur ^= 1;
#pragma unroll
      for (int kk = 0; kk < 2; ++kk)
#pragma unroll
        for (int ms = 0; ms < 4; ++ms) yf[kk][ms] = yn[kk][ms];
    }
  }

#pragma unroll
  for (int i = 0; i < 2; ++i) {
    float* ob = out + (((size_t)b * H_ + h0 + i) * K_) * D_;
    const int hb = (h0 + i) * 8 + b;
#pragma unroll
    for (int ms = 0; ms < 4; ++ms)
#pragma unroll
      for (int nt = 0; nt < 4; ++nt) {
        int col = nt * 16 + m16;
        float bf = bfin[hb * D_ + col];
#pragma unroll
        for (int r = 0; r < 4; ++r) {
          int row = kt * 256 + wave * 64 + ms * 16 + quad * 4 + r;
          ob[(size_t)row * D_ + col] = acc[ms][i][nt][r] + bf;
        }
      }
  }
}

// =========================================================================
// Fallback f32 path (round-1 kernels), used if ws_size is too small
// =========================================================================
__global__ __launch_bounds__(256) void k_gram(const float* __restrict__ x,
                                              float* __restrict__ G,
                                              float* __restrict__ svec) {
  const int it = blockIdx.x, jt = blockIdx.y, b = blockIdx.z;
  if (jt < it) return;
  __shared__ float Xi[16][64];
  __shared__ float Xj[16][64];
  const float* Xb = x + (size_t)b * K_ * IN_;
  const int tx = threadIdx.x, ty = threadIdx.y;
  const int tid = ty * 16 + tx;
  const int i0 = it * 64, j0 = jt * 64;
  const bool diag = (it == jt);
  float acc[4][4] = {};
  float ssum = 0.f;
  for (int k0 = 0; k0 < K_; k0 += 16) {
#pragma unroll
    for (int r = 0; r < 4; ++r) {
      int idx = tid + 256 * r;
      int kk = idx >> 6, cc = idx & 63;
      const float* row = Xb + (size_t)(k0 + kk) * IN_;
      Xi[kk][cc] = row[i0 + cc];
      Xj[kk][cc] = row[j0 + cc];
    }
    __syncthreads();
#pragma unroll
    for (int kk = 0; kk < 16; ++kk) {
      float a[4], bb[4];
#pragma unroll
      for (int u = 0; u < 4; ++u) a[u] = Xi[kk][ty * 4 + u];
#pragma unroll
      for (int u = 0; u < 4; ++u) bb[u] = Xj[kk][tx * 4 + u];
#pragma unroll
      for (int u = 0; u < 4; ++u)
#pragma unroll
        for (int w = 0; w < 4; ++w) acc[u][w] += a[u] * bb[w];
    }
    if (diag && tid < 64) {
#pragma unroll
      for (int kk = 0; kk < 16; ++kk) ssum += Xi[kk][tid];
    }
    __syncthreads();
  }
  float* Gb = G + (size_t)b * IN_ * IN_;
#pragma unroll
  for (int u = 0; u < 4; ++u)
#pragma unroll
    for (int w = 0; w < 4; ++w) {
      int gi = i0 + ty * 4 + u, gj = j0 + tx * 4 + w;
      Gb[(size_t)gi * IN_ + gj] = acc[u][w];
      if (!diag) Gb[(size_t)gj * IN_ + gi] = acc[u][w];
    }
  if (diag && tid < 64) svec[b * IN_ + i0 + tid] = ssum;
}

__global__ __launch_bounds__(256) void k_aall(const float* __restrict__ Wq,
                                              const float* __restrict__ G,
                                              float* __restrict__ Aall) {
  const int jt = blockIdx.x;
  const int h = blockIdx.y, b = blockIdx.z;
  __shared__ float Ws[16][64];
  __shared__ float Gs[16][64];
  const float* Gb = G + (size_t)b * IN_ * IN_;
  const int tx = threadIdx.x, ty = threadIdx.y;
  const int tid = ty * 16 + tx;
  float acc[4][4] = {};
  for (int c0 = 0; c0 < IN_; c0 += 16) {
#pragma unroll
    for (int r = 0; r < 4; ++r) {
      int idx = tid + 256 * r;
      int kk = idx >> 6, cc = idx & 63;
      Ws[kk][cc] = Wq[(size_t)(c0 + kk) * HD_ + h * D_ + cc];
      Gs[kk][cc] = Gb[(size_t)(c0 + kk) * IN_ + jt * 64 + cc];
    }
    __syncthreads();
#pragma unroll
    for (int kk = 0; kk < 16; ++kk) {
      float a[4], bb[4];
#pragma unroll
      for (int u = 0; u < 4; ++u) a[u] = Ws[kk][ty * 4 + u];
#pragma unroll
      for (int u = 0; u < 4; ++u) bb[u] = Gs[kk][tx * 4 + u];
#pragma unroll
      for (int u = 0; u < 4; ++u)
#pragma unroll
        for (int w = 0; w < 4; ++w) acc[u][w] += a[u] * bb[w];
    }
    __syncthreads();
  }
  const int hb = h * B_ + b;
  float* Ahb = Aall + (size_t)hb * D_ * IN_;
#pragma unroll
  for (int u = 0; u < 4; ++u)
#pragma unroll
    for (int w = 0; w < 4; ++w)
      Ahb[(size_t)(ty * 4 + u) * IN_ + jt * 64 + tx * 4 + w] = acc[u][w];
}

__global__ __launch_bounds__(256) void k_attn_f32(
    const float* __restrict__ Wq, const float* __restrict__ Wk,
    const float* __restrict__ Wv, const float* __restrict__ Wp,
    const float* __restrict__ bq, const float* __restrict__ bk,
    const float* __restrict__ bv, const float* __restrict__ gamma,
    const float* __restrict__ Aall, const float* __restrict__ svec,
    float* __restrict__ Wfin, float* __restrict__ bfin) {
  const int h = blockIdx.x, b = blockIdx.y;
  const int hb = h * B_ + b;
  const int tx = threadIdx.x, ty = threadIdx.y;
  const int tid = ty * 16 + tx;
  __shared__ float Ast[64][17];
  __shared__ float Ws[16][64];
  __shared__ float Esh[64][65];
  __shared__ float t1[64], t2[64];
  const float* Ahb = Aall + (size_t)hb * D_ * IN_;
  if (tid < 64) {
    float a2 = 0.f;
    for (int c = 0; c < IN_; ++c)
      a2 += svec[b * IN_ + c] * Wk[(size_t)c * HD_ + h * D_ + tid];
    t1[tid] = a2;
  } else if (tid < 128) {
    int d = tid - 64;
    float a2 = 0.f;
    for (int c = 0; c < IN_; ++c)
      a2 += svec[b * IN_ + c] * Wq[(size_t)c * HD_ + h * D_ + d];
    t2[d] = a2;
  }
  float acc[4][4] = {};
  for (int c0 = 0; c0 < IN_; c0 += 16) {
#pragma unroll
    for (int r = 0; r < 4; ++r) {
      int idx = tid + 256 * r;
      int dd = idx >> 4, kk = idx & 15;
      Ast[dd][kk] = Ahb[(size_t)dd * IN_ + c0 + kk];
      int kk2 = idx >> 6, ee = idx & 63;
      Ws[kk2][ee] = Wk[(size_t)(c0 + kk2) * HD_ + h * D_ + ee];
    }
    __syncthreads();
#pragma unroll
    for (int kk = 0; kk < 16; ++kk) {
      float a[4], bb[4];
#pragma unroll
      for (int u = 0; u < 4; ++u) a[u] = Ast[ty * 4 + u][kk];
#pragma unroll
      for (int u = 0; u < 4; ++u) bb[u] = Ws[kk][tx * 4 + u];
#pragma unroll
      for (int u = 0; u < 4; ++u)
#pragma unroll
        for (int w = 0; w < 4; ++w) acc[u][w] += a[u] * bb[w];
    }
    __syncthreads();
  }
#pragma unroll
  for (int u = 0; u < 4; ++u) {
    int d = ty * 4 + u;
    float bqd = bq[h * D_ + d];
    float t2d = t2[d];
#pragma unroll
    for (int w = 0; w < 4; ++w) {
      int e = tx * 4 + w;
      float bke = bk[h * D_ + e];
      Esh[d][e] = acc[u][w] + bqd * t1[e] + t2d * bke + (float)K_ * bqd * bke;
    }
  }
  __syncthreads();
  if (tid < 64) {
    float m = -1e30f;
    for (int e = 0; e < 64; ++e) m = fmaxf(m, Esh[tid][e]);
    float ssum = 0.f;
    for (int e = 0; e < 64; ++e) {
      float p = __expf(Esh[tid][e] - m);
      Esh[tid][e] = p;
      ssum += p;
    }
    float inv = 1.f / ssum;
    for (int e = 0; e < 64; ++e) Esh[tid][e] *= inv;
  }
  __syncthreads();
  const float g = gamma[h];
  const float inv1g = 1.f / (1.f + g);
  if (tid < 64) {
    float a2 = 0.f;
    for (int e = 0; e < 64; ++e) a2 += bv[h * D_ + e] * Esh[tid][e];
    bfin[hb * D_ + tid] = g * a2 * inv1g;
  }
  float* Wf = Wfin + (size_t)hb * IN_ * D_;
  for (int it2 = 0; it2 < 128; ++it2) {
    int idx = tid + 256 * it2;
    int c = idx >> 6, q = idx & 63;
    const float* Wvr = Wv + (size_t)c * HD_ + h * D_;
    float a2 = 0.f;
#pragma unroll
    for (int e = 0; e < 64; ++e) a2 += Wvr[e] * Esh[q][e];
    Wf[idx] = (g * a2 + Wp[(size_t)c * D_ + q]) * inv1g;
  }
}

__global__ __launch_bounds__(256) void k_out_f32(const float* __restrict__ y,
                                                 const float* __restrict__ Wfin,
                                                 const float* __restrict__ bfin,
                                                 float* __restrict__ out) {
  const int kt = blockIdx.x;
  const int hb = blockIdx.y;
  const int h = hb >> 3, b = hb & 7;
  __shared__ float Ys[64][17];
  __shared__ float Ws[16][64];
  const int tx = threadIdx.x, ty = threadIdx.y;
  const int tid = ty * 16 + tx;
  const float* Yb = y + (size_t)b * K_ * IN_;
  const float* Wf = Wfin + (size_t)hb * IN_ * D_;
  const int k0 = kt * 64;
  float acc[4][4] = {};
  for (int c0 = 0; c0 < IN_; c0 += 16) {
#pragma unroll
    for (int r = 0; r < 4; ++r) {
      int idx = tid + 256 * r;
      int rr = idx >> 4, kk = idx & 15;
      Ys[rr][kk] = Yb[(size_t)(k0 + rr) * IN_ + c0 + kk];
      int kk2 = idx >> 6, qq = idx & 63;
      Ws[kk2][qq] = Wf[(size_t)(c0 + kk2) * D_ + qq];
    }
    __syncthreads();
#pragma unroll
    for (int kk = 0; kk < 16; ++kk) {
      float a[4], bb[4];
#pragma unroll
      for (int u = 0; u < 4; ++u) a[u] = Ys[ty * 4 + u][kk];
#pragma unroll
      for (int u = 0; u < 4; ++u) bb[u] = Ws[kk][tx * 4 + u];
#pragma unroll
      for (int u = 0; u < 4; ++u)
#pragma unroll
        for (int w = 0; w < 4; ++w) acc[u][w] += a[u] * bb[w];
    }
    __syncthreads();
  }
  float* ob = out + (((size_t)b * H_ + h) * K_ + k0) * D_;
#pragma unroll
  for (int u = 0; u < 4; ++u) {
    int k = ty * 4 + u;
#pragma unroll
    for (int w = 0; w < 4; ++w) {
      int q = tx * 4 + w;
      ob[(size_t)k * D_ + q] = acc[u][w] + bfin[hb * D_ + q];
    }
  }
}

// =========================================================================
extern "C" void kernel_launch(void* const* d_in, const int* in_sizes, int n_in,
                              void* d_out, int out_size, void* d_ws,
                              size_t ws_size, hipStream_t stream) {
  const float* x = (const float*)d_in[0];
  const float* y = (const float*)d_in[1];
  const float* Wq = (const float*)d_in[2];
  const float* bq = (const float*)d_in[3];
  const float* Wk = (const float*)d_in[4];
  const float* bk = (const float*)d_in[5];
  const float* Wv = (const float*)d_in[6];
  const float* bv = (const float*)d_in[7];
  const float* Wp = (const float*)d_in[8];
  const float* gm = (const float*)d_in[9];
  float* out = (float*)d_out;

  const size_t NEED = 86016000;
  if (ws_size >= NEED) {
    char* w = (char*)d_ws;
    u16* xt_hi = (u16*)(w);           // phase 1
    u16* Ahi = (u16*)(w);             // phase 2 aliases
    u16* Alo = (u16*)(w + 4194304);
    u16* Wft = (u16*)(w + 8388608);
    u16* xt_lo = (u16*)(w + 33554432);
    u16* yb = (u16*)(w + 33554432);   // phase 2 alias of xt_lo
    float* G = (float*)(w + 67108864);
    u16* Pbf = (u16*)(w + 67108864);  // aliases G (free after k_cvt_g)
    u16* Ghi = (u16*)(w + 75497472);
    u16* Glo = (u16*)(w + 79691776);
    u16* Wqt_hi = (u16*)(w + 83886080);
    u16* Wqt_lo = (u16*)(w + 84410368);
    u16* Wkt_hi = (u16*)(w + 84934656);
    u16* Wkt_lo = (u16*)(w + 85458944);
    float* bfin = (float*)(w + 85983232);
    float* svec = (float*)(w + 85999616);

    hipMemsetAsync(G, 0, 8388608, stream);
    hipMemsetAsync(svec, 0, 16384, stream);
    k_cvt_w<<<dim3(8, 8, 2), 256, 0, stream>>>(Wq, Wk, Wqt_hi, Wqt_lo, Wkt_hi,
                                               Wkt_lo);
    k_cvt_x<<<dim3(64, 8, 8), 256, 0, stream>>>(x, xt_hi, xt_lo, svec);
    k_gram_mfma<<<dim3(640), 256, 0, stream>>>(xt_hi, xt_lo, G);
    k_cvt_y<<<dim3(8192), 256, 0, stream>>>(y, yb);
    k_cvt_g<<<dim3(8, 8, 8), 256, 0, stream>>>(G, Ghi, Glo);
    k_aall_mfma<<<dim3(8, 64), 256, 0, stream>>>(Wqt_hi, Wqt_lo, Ghi, Glo, Ahi,
                                                 Alo);
    k_attn3<<<dim3(8, 8), 256, 0, stream>>>(Ahi, Alo, Wqt_hi, Wqt_lo, Wkt_hi,
                                            Wkt_lo, bq, bk, bv, gm, svec, Pbf,
                                            bfin);
    k_wft<<<dim3(4, 64), 256, 0, stream>>>(Pbf, Wv, Wp, gm, Wft);
    k_out_mfma<<<dim3(16, 32), 256, 0, stream>>>(yb, Wft, bfin, out);
  } else {
    float* ws = (float*)d_ws;
    float* G = ws;
    float* Aall = ws + 2097152;
    float* Wfin = ws + 4194304;
    float* bfin = ws + 6291456;
    float* svec = ws + 6295552;
    dim3 blk(16, 16);
    k_gram<<<dim3(8, 8, 8), blk, 0, stream>>>(x, G, svec);
    k_aall<<<dim3(8, 8, 8), blk, 0, stream>>>(Wq, G, Aall);
    k_attn_f32<<<dim3(8, 8), blk, 0, stream>>>(Wq, Wk, Wv, Wp, bq, bk, bv, gm,
                                               Aall, svec, Wfin, bfin);
    k_out_f32<<<dim3(64, 64), blk, 0, stream>>>(y, Wfin, bfin, out);
  }
}